// Round 5
// baseline (251.005 us; speedup 1.0000x reference)
//
#include <hip/hip_runtime.h>
#include <hip/hip_bf16.h>
#include <stdint.h>

// out[b, seg, np, chunk, p, 4, 4] = mean over chunk frames of [x;1][x;1]^T
// (cov + mu muT == E[y yT]).  stypes 0/1/2 have chunk len 136/68/45 and map
// to out segs {0},{1,2},{3,4,5}.
//
// Fully fused, one block per b (256 blocks x 1024 thr = 1 block/CU):
//  - pieces = partition of [0,2048) at union of all chunk boundaries, <=50
//    frames (never cross any chunk edge)
//  - double-buffered LDS staging via global_load_lds width 16 (prefetch p+1
//    while computing p)
//  - thread quad (4 lanes) owns one (joint,moment) cell; per piece: quad
//    shfl-reduce, q==0 lane RMWs the 3 live (stype,chunk) rows
//  - 6-slot ring of chunk accumulators (slot = st*2 + ch&1); on a chunk's
//    last piece: finalize+store its 4x4s (float4, coalesced), zero the row
// No workspace, no second kernel.

#define NPIECE_MAX 64
// nibble table: row r of the 4x4 -> moment index in red row (9 = dummy)
#define IDXPK 0x9210287517640543ull

struct Tab {
    int n;                         // #pieces (56 for T=2048)
    uint32_t p[NPIECE_MAX];        // f0 | (len<<16)
    uint32_t meta[NPIECE_MAX];     // c0 | c1<<4 | c2<<8 | endmask<<12
};

__global__ __launch_bounds__(1024) void fused_kernel(const float* __restrict__ x,
                                                     float* __restrict__ out, Tab tab) {
    __shared__ float sx[2][3760];        // 2 x 15 KB staging
    __shared__ float red[6 * 225 + 16];  // ring rows + pad for dummy idx 9
    int tid = threadIdx.x;
    int b   = blockIdx.x;
    const float* xb = x + (size_t)b * 153600;
    int wv = tid >> 6, ln = tid & 63;

    for (int i = tid; i < 6 * 225 + 16; i += 1024) red[i] = 0.f;

    // issue piece 0 into sx[0]
    {
        uint32_t pk = tab.p[0];
        int f0 = pk & 0xffff, L = (int)(pk >> 16);
        int w0 = f0 * 75, base_f = w0 & ~3;
        int nv4 = (w0 - base_f + L * 75 + 3) >> 2;
        const float4* src = (const float4*)(xb + base_f);
        int i = wv * 64 + ln;
        if (i < nv4)
            __builtin_amdgcn_global_load_lds(
                (const __attribute__((address_space(1))) void*)(src + i),
                (__attribute__((address_space(3))) void*)(&sx[0][wv * 256]), 16, 0, 0);
    }

    // per-thread cell constants: cell = j*9 + si, quad index q
    int cell = tid >> 2, q = tid & 3;
    int j  = cell / 9, si = cell - j * 9;
    int k3 = si - 3;
    int ia = (si < 3) ? si : (k3 < 3 ? 0 : (k3 < 5 ? 1 : 2));
    int ib = (si < 3) ? si : (k3 < 3 ? k3 : (k3 < 5 ? k3 - 2 : 2));
    bool single = (si < 3);
    int off0 = q * 75 + j * 3;

    __syncthreads();   // piece 0 loaded (vmcnt drained), red zeroed

    int n = tab.n;
    for (int p = 0; p < n; ++p) {
        uint32_t pk = tab.p[p];
        int f0 = pk & 0xffff, L = (int)(pk >> 16);
        int shift = (f0 * 75) & 3;
        int buf = p & 1;

        // prefetch piece p+1 into the other buffer (in flight during compute)
        if (p + 1 < n) {
            uint32_t pk2 = tab.p[p + 1];
            int g0 = pk2 & 0xffff, L2 = (int)(pk2 >> 16);
            int w0 = g0 * 75, base_f = w0 & ~3;
            int nv4 = (w0 - base_f + L2 * 75 + 3) >> 2;
            const float4* src = (const float4*)(xb + base_f);
            int i = wv * 64 + ln;
            if (i < nv4)
                __builtin_amdgcn_global_load_lds(
                    (const __attribute__((address_space(1))) void*)(src + i),
                    (__attribute__((address_space(3))) void*)(&sx[buf ^ 1][wv * 256]), 16, 0, 0);
        }

        uint32_t mt = tab.meta[p];
        if (tid < 900) {
            const float* s = &sx[buf][shift];
            float acc = 0.f;
            int off = off0;
            for (int t = q; t < L; t += 4, off += 300) {
                float a  = s[off + ia];
                float bb = s[off + ib];
                acc += single ? a : a * bb;
            }
            acc += __shfl_xor(acc, 1);
            acc += __shfl_xor(acc, 2);
            if (q == 0) {
                int c0 = mt & 15, c1 = (mt >> 4) & 15, c2 = (mt >> 8) & 15;
                red[((c0 & 1)) * 225 + cell]     += acc;
                red[(2 + (c1 & 1)) * 225 + cell] += acc;
                red[(4 + (c2 & 1)) * 225 + cell] += acc;
            }
        }

        uint32_t em = (mt >> 12) & 7;   // wave-uniform
        if (em) {
            __syncthreads();            // RMWs visible
            float4* ob4 = (float4*)(out + (size_t)b * 36000);
            for (int st = 0; st < 3; ++st) {
                if (!((em >> st) & 1)) continue;
                int ch  = (mt >> (4 * st)) & 15;
                int ns  = (st == 0) ? 136 : (st == 1) ? 68 : 45;
                int nfr = (ch == 14) ? (2048 - 14 * ns) : ns;
                float inv = 1.0f / (float)nfr;
                int slot = st * 2 + (ch & 1);
                int ndup = st + 1;                       // 1,2,3 dup segs
                int so0  = (st == 0) ? 0 : (st == 1) ? 1 : 3;
                int tot  = ndup * 100;                   // float4 count
                for (int i2 = tid; i2 < tot; i2 += 1024) {
                    int dup = i2 / 100;
                    int r2  = i2 - dup * 100;            // jj*4 + r
                    int jj  = r2 >> 2, r = r2 & 3;
                    int np_ = jj / 5, pp = jj - np_ * 5;
                    const float* rb = &red[slot * 225 + jj * 9];
                    uint64_t pkk = IDXPK >> (16 * r);
                    float4 v;
                    v.x = rb[(int)(pkk & 15)] * inv;
                    v.y = rb[(int)((pkk >> 4) & 15)] * inv;
                    v.z = rb[(int)((pkk >> 8) & 15)] * inv;
                    v.w = (r == 3) ? 1.0f : rb[(int)((pkk >> 12) & 15)] * inv;
                    ob4[(so0 + dup) * 1500 + np_ * 300 + ch * 20 + pp * 4 + r] = v;
                }
            }
            __syncthreads();            // writeout reads done
            if (tid < 225) {
                for (int st = 0; st < 3; ++st) {
                    if (!((em >> st) & 1)) continue;
                    int ch = (mt >> (4 * st)) & 15;
                    red[(st * 2 + (ch & 1)) * 225 + tid] = 0.f;
                }
            }
        }
        __syncthreads();  // p+1 loaded (vmcnt drain), stage p free, zeros visible
    }
}

// ---------------- Host ----------------
static void build_tab(Tab& tab) {
    unsigned char isb[2049];
    for (int i = 0; i <= 2048; ++i) isb[i] = 0;
    isb[2048] = 1;
    for (int k = 1; k <= 14; ++k) { isb[45 * k] = 1; isb[68 * k] = 1; isb[136 * k] = 1; }
    int n = 0, prev = 0;
    for (int f = 1; f <= 2048; ++f) {
        if (!isb[f]) continue;
        int len = f - prev;
        int npc = (len + 49) / 50;
        int base = len / npc, rem = len % npc;
        int s = prev;
        for (int i = 0; i < npc && n < NPIECE_MAX; ++i) {
            int l = base + (i < rem ? 1 : 0);
            tab.p[n++] = (uint32_t)(s | (l << 16));
            s += l;
        }
        prev = f;
    }
    tab.n = n;   // 56
    const int nst[3] = {136, 68, 45};
    for (int i = 0; i < n; ++i) {
        int f0 = tab.p[i] & 0xffff;
        int f1 = f0 + (int)(tab.p[i] >> 16);
        uint32_t m = 0;
        for (int st = 0; st < 3; ++st) {
            int ns = nst[st];
            int c = f0 / ns; if (c > 14) c = 14;
            int bnd = (c == 14) ? 2048 : (c + 1) * ns;
            m |= (uint32_t)c << (4 * st);
            if (f1 == bnd) m |= 1u << (12 + st);
        }
        tab.meta[i] = m;
    }
}

extern "C" void kernel_launch(void* const* d_in, const int* in_sizes, int n_in,
                              void* d_out, int out_size, void* d_ws, size_t ws_size,
                              hipStream_t stream) {
    const float* x = (const float*)d_in[0];
    float* out = (float*)d_out;
    Tab tab;
    build_tab(tab);
    fused_kernel<<<256, 1024, 0, stream>>>(x, out, tab);
}